// Round 4
// baseline (425.583 us; speedup 1.0000x reference)
//
#include <hip/hip_runtime.h>
#include <stdint.h>

#define BATCH 64
#define CDIM  64
#define NPTS  1024
#define ODIM  128
#define KNN   49
#define KNNP  52      // padded knn row stride (16B-aligned: 52*4=208=16*13)
#define BNEPS 1e-5f

typedef __attribute__((ext_vector_type(8))) short bf16x8;   // 8 bf16 (4 VGPRs)
typedef __attribute__((ext_vector_type(4))) float f32x4;

// ---- workspace layout (bytes) ----
#define O_XF   0
#define SZ_XF  (BATCH*64*2*64*8*4)        // 16,777,216  bf16 hi/lo fragments
#define O_SQ   (O_XF + SZ_XF)
#define SZ_SQ  (BATCH*NPTS*4)             // 262,144    per-col squared norms
#define O_KNN  (O_SQ + SZ_SQ)
#define SZ_KNN (BATCH*NPTS*KNNP*4)        // 13,631,488 knn indices (padded)
#define O_Z    (O_KNN + SZ_KNN)
#define SZ_Z   (BATCH*NPTS*CDIM*4)        // 16,777,216 aggregated features
#define WS_NEED ((size_t)(O_Z + SZ_Z))    // 47,448,064

// out[b*O+o] = beta - gamma*mean*rsqrt(var+eps)   (BN constant of pooled mean)
__global__ void gcn_init(const float* __restrict__ gamma, const float* __restrict__ beta,
                         const float* __restrict__ rmean, const float* __restrict__ rvar,
                         float* __restrict__ out) {
    int i = blockIdx.x * 256 + threadIdx.x;
    if (i < BATCH * ODIM) {
        int o = i & (ODIM - 1);
        out[i] = beta[o] - gamma[o] * rmean[o] * rsqrtf(rvar[o] + BNEPS);
    }
}

// ======================= K0: bf16 hi/lo split + MFMA-fragment swizzle + sq ==============
__global__ __launch_bounds__(256) void k0_split(const float* __restrict__ X,
                                                uint32_t* __restrict__ XF,
                                                float* __restrict__ sq) {
    const int b    = blockIdx.x >> 4;
    const int t16  = (blockIdx.x & 15) * 4 + (threadIdx.x >> 6);
    const int lane = threadIdx.x & 63;
    const int n    = t16 * 16 + (lane & 15);
    const int cg   = lane >> 4;
    const float* Xb = X + (size_t)b * CDIM * NPTS;
    float s = 0.f;
    for (int ks = 0; ks < 2; ks++) {
        uint32_t hi[4], lo[4];
#pragma unroll
        for (int dj = 0; dj < 4; dj++) {
            uint32_t hw[2], lw[2];
#pragma unroll
            for (int e = 0; e < 2; e++) {
                int c = ks * 32 + cg * 8 + dj * 2 + e;
                float x = Xb[(size_t)c * NPTS + n];
                s += x * x;
                uint32_t u  = __float_as_uint(x);
                uint32_t hr = (u + 0x7FFFu + ((u >> 16) & 1u)) >> 16;   // RTNE bf16
                float    hf = __uint_as_float(hr << 16);
                uint32_t ul = __float_as_uint(x - hf);
                uint32_t lr = (ul + 0x7FFFu + ((ul >> 16) & 1u)) >> 16;
                hw[e] = hr; lw[e] = lr;
            }
            hi[dj] = hw[0] | (hw[1] << 16);
            lo[dj] = lw[0] | (lw[1] << 16);
        }
        size_t entry = ((size_t)(b * 64 + t16) * 2 + ks) * 64 + lane;
        uint32_t* p = XF + entry * 8;
        *(uint4*)p       = make_uint4(hi[0], hi[1], hi[2], hi[3]);
        *(uint4*)(p + 4) = make_uint4(lo[0], lo[1], lo[2], lo[3]);
    }
    s += __shfl_xor(s, 16, 64);
    s += __shfl_xor(s, 32, 64);
    if (lane < 16) sq[b * NPTS + n] = s;
}

// ======================= K1: MFMA Gram + radix-histogram 49-select -> knn ===============
// 512 threads (8 waves). Keys truncated to top-16 bits of the monotone map and
// packed 2 rows/uint (pair p = row>>1, wave w handles pair w). Selection: two
// 8-bit LDS-atomic histogram passes per row (no serial binary-search chain).
__global__ __launch_bounds__(512, 4) void k1_gram_select(const uint32_t* __restrict__ XF,
                                                         const float* __restrict__ sq,
                                                         int* __restrict__ knn) {
    __shared__ uint32_t s_pk[8 * 1024];              // 32 KB packed keys; reused for hists
    const int b    = blockIdx.x >> 6;
    const int rt   = blockIdx.x & 63;                // 16-row tile
    const int wave = threadIdx.x >> 6, lane = threadIdx.x & 63;
    const int q = lane >> 4, l15 = lane & 15;

    // A fragments (rows rt*16..+15), shared by all waves
    bf16x8 ahi[2], alo[2];
#pragma unroll
    for (int ks = 0; ks < 2; ks++) {
        const uint32_t* p = XF + (((size_t)(b * 64 + rt) * 2 + ks) * 64 + lane) * 8;
        ahi[ks] = *(const bf16x8*)p;
        alo[ks] = *(const bf16x8*)(p + 4);
    }
    const float* sqb = sq + b * NPTS;

#pragma unroll
    for (int tt = 0; tt < 8; tt++) {                 // wave's 8 col-tiles
        const int t16 = wave * 8 + tt;
        f32x4 acc = {0.f, 0.f, 0.f, 0.f};
#pragma unroll
        for (int ks = 0; ks < 2; ks++) {
            const uint32_t* p = XF + (((size_t)(b * 64 + t16) * 2 + ks) * 64 + lane) * 8;
            bf16x8 bhi = *(const bf16x8*)p;
            bf16x8 blo = *(const bf16x8*)(p + 4);
            acc = __builtin_amdgcn_mfma_f32_16x16x32_bf16(ahi[ks], bhi, acc, 0, 0, 0);
            acc = __builtin_amdgcn_mfma_f32_16x16x32_bf16(alo[ks], bhi, acc, 0, 0, 0);
            acc = __builtin_amdgcn_mfma_f32_16x16x32_bf16(ahi[ks], blo, acc, 0, 0, 0);
        }
        const int col  = t16 * 16 + l15;
        const float sqv = sqb[col];
        uint32_t k16[4];
#pragma unroll
        for (int i = 0; i < 4; i++) {
            int row = q * 4 + i;                     // C layout: row=(lane>>4)*4+reg
            float d = sqv - 2.f * acc[i];            // sq_r dropped (row-monotone)
            if (col == rt * 16 + row) d = __uint_as_float(0x7F800000u);  // self
            uint32_t u = __float_as_uint(d);
            uint32_t key = ((int)u < 0) ? ~u : (u | 0x80000000u);
            k16[i] = key >> 16;                      // 16-bit monotone key
        }
        const int p0 = 2 * q, p1 = 2 * q + 1;        // row pairs
        s_pk[p0 * 1024 + (col ^ ((p0 & 3) << 3))] = k16[0] | (k16[1] << 16);
        s_pk[p1 * 1024 + (col ^ ((p1 & 3) << 3))] = k16[2] | (k16[3] << 16);
    }
    __syncthreads();

    // ---- load this wave's packed row-pair into registers ----
    uint32_t pk[16];
    {
        const int sw = (wave & 3) << 3;
#pragma unroll
        for (int tt = 0; tt < 16; tt++)
            pk[tt] = s_pk[wave * 1024 + ((tt * 64 + lane) ^ sw)];
    }
    __syncthreads();                                 // s_pk now dead -> hist space

    uint32_t* hist = &s_pk[wave * 256];              // per-wave 256-bin histogram
    const unsigned long long ltmask = (1ull << lane) - 1ull;

#pragma unroll
    for (int r = 0; r < 2; r++) {
        const int row = wave * 2 + r;
        uint32_t k[16];
#pragma unroll
        for (int tt = 0; tt < 16; tt++)
            k[tt] = r ? (pk[tt] >> 16) : (pk[tt] & 0xFFFFu);

        // ---- pass 1: histogram of top byte ----
        *(uint4*)&hist[4 * lane] = make_uint4(0, 0, 0, 0);
#pragma unroll
        for (int tt = 0; tt < 16; tt++)
            atomicAdd(&hist[k[tt] >> 8], 1u);
        uint4 h = *(uint4*)&hist[4 * lane];
        uint32_t lsum = h.x + h.y + h.z + h.w;
        uint32_t incl = lsum;
#pragma unroll
        for (int off = 1; off < 64; off <<= 1) {
            uint32_t v = (uint32_t)__shfl_up((int)incl, off, 64);
            incl += (lane >= off) ? v : 0u;
        }
        uint32_t excl = incl - lsum;
        {
            unsigned long long m = __ballot(incl >= KNN);
            int ltgt = __ffsll((long long)m) - 1;
            uint32_t c0 = excl, c1 = c0 + h.x, c2 = c1 + h.y, c3 = c2 + h.z;
            int joff; uint32_t cb;
            if      (c1 >= KNN) { joff = 0; cb = c0; }
            else if (c2 >= KNN) { joff = 1; cb = c1; }
            else if (c3 >= KNN) { joff = 2; cb = c2; }
            else                { joff = 3; cb = c3; }
            int bstar      = __shfl(4 * lane + joff, ltgt, 64);
            uint32_t cless = (uint32_t)__shfl((int)cb, ltgt, 64);

            // ---- pass 2: histogram of low byte within bin bstar ----
            *(uint4*)&hist[4 * lane] = make_uint4(0, 0, 0, 0);
#pragma unroll
            for (int tt = 0; tt < 16; tt++)
                if ((int)(k[tt] >> 8) == bstar) atomicAdd(&hist[k[tt] & 255u], 1u);
            uint4 h2 = *(uint4*)&hist[4 * lane];
            uint32_t lsum2 = h2.x + h2.y + h2.z + h2.w;
            uint32_t incl2 = lsum2;
#pragma unroll
            for (int off = 1; off < 64; off <<= 1) {
                uint32_t v = (uint32_t)__shfl_up((int)incl2, off, 64);
                incl2 += (lane >= off) ? v : 0u;
            }
            uint32_t excl2 = incl2 - lsum2;
            unsigned long long m2 = __ballot(cless + incl2 >= KNN);
            int ltgt2 = __ffsll((long long)m2) - 1;
            uint32_t d0 = cless + excl2, d1 = d0 + h2.x, d2 = d1 + h2.y, d3 = d2 + h2.z;
            int joff2; uint32_t db;
            if      (d1 >= KNN) { joff2 = 0; db = d0; }
            else if (d2 >= KNN) { joff2 = 1; db = d1; }
            else if (d3 >= KNN) { joff2 = 2; db = d2; }
            else                { joff2 = 3; db = d3; }
            int cstar        = __shfl(4 * lane + joff2, ltgt2, 64);
            uint32_t cntless = (uint32_t)__shfl((int)db, ltgt2, 64);

            const uint32_t vstar = ((uint32_t)bstar << 8) | (uint32_t)cstar;
            const int need = KNN - (int)cntless;     // ties by ascending index

            // ---- emit indices ----
            int base = 0, eqtaken = 0;
            int* kout = knn + ((size_t)b * NPTS + rt * 16 + row) * KNNP;
#pragma unroll
            for (int tt = 0; tt < 16; tt++) {
                bool islt = k[tt] < vstar, iseq = k[tt] == vstar;
                unsigned long long meq = __ballot(iseq);
                int eqrank = eqtaken + __popcll(meq & ltmask);
                bool sel = islt || (iseq && eqrank < need);
                unsigned long long msel = __ballot(sel);
                if (sel) kout[base + __popcll(msel & ltmask)] = tt * 64 + lane;
                base    += __popcll(msel);
                eqtaken += __popcll(meq);
            }
        }
    }
}

// ======================= K2a: neighbor aggregation -> z =================================
// lane = r2*16 + kb*4 + g : 4 rows per iteration, 2-step shuffle reduce over kb.
__global__ __launch_bounds__(256) void k2a_aggregate(const float* __restrict__ X,
                                                     const int* __restrict__ knn,
                                                     float* __restrict__ z) {
    __shared__ float XT[16 * 1024];                  // 64 KB, [n][16ch] quad-swizzled
    const int b = blockIdx.x >> 3, cg = (blockIdx.x >> 1) & 3, half = blockIdx.x & 1;
    const int t = threadIdx.x;
    const float* Xb = X + ((size_t)b * CDIM + cg * 16) * NPTS;
#pragma unroll
    for (int nn = 0; nn < 4; nn++) {                 // stage 16 ch x 1024 cols transposed
        int n = nn * 256 + t;
#pragma unroll
        for (int g = 0; g < 4; g++) {
            float4 v;
            v.x = Xb[(size_t)(4 * g + 0) * NPTS + n];
            v.y = Xb[(size_t)(4 * g + 1) * NPTS + n];
            v.z = Xb[(size_t)(4 * g + 2) * NPTS + n];
            v.w = Xb[(size_t)(4 * g + 3) * NPTS + n];
            int qp = g ^ ((n >> 1) & 3);             // full 32-bank spread for b128
            *(float4*)&XT[n * 16 + qp * 4] = v;
        }
    }
    __syncthreads();
    const int wave = t >> 6, lane = t & 63;
    const int r2 = lane >> 4, kb = (lane >> 2) & 3, g = lane & 3;
    for (int rr = 0; rr < 32; rr++) {                // 128 rows per wave, 4 at a time
        const int row = half * 512 + wave * 128 + rr * 4 + r2;
        const int* kr = knn + ((size_t)b * NPTS + row) * KNNP;
        float4 s = {0.f, 0.f, 0.f, 0.f};
#pragma unroll
        for (int cs = 0; cs < 3; cs++) {             // aligned dwordx4 knn loads
            int4 j4 = *(const int4*)&kr[(kb + 4 * cs) * 4];
            int js[4] = {j4.x, j4.y, j4.z, j4.w};
#pragma unroll
            for (int e = 0; e < 4; e++) {
                int j = js[e];
                float4 v = *(const float4*)&XT[j * 16 + ((g ^ ((j >> 1) & 3)) << 2)];
                s.x += v.x; s.y += v.y; s.z += v.z; s.w += v.w;
            }
        }
        if (kb == 0) {                               // tail k = 48
            int j = kr[48];
            float4 v = *(const float4*)&XT[j * 16 + ((g ^ ((j >> 1) & 3)) << 2)];
            s.x += v.x; s.y += v.y; s.z += v.z; s.w += v.w;
        }
#pragma unroll
        for (int off = 4; off <= 8; off <<= 1) {     // reduce over kb (bits [3:2])
            s.x += __shfl_xor(s.x, off, 64);
            s.y += __shfl_xor(s.y, off, 64);
            s.z += __shfl_xor(s.z, off, 64);
            s.w += __shfl_xor(s.w, off, 64);
        }
        if (kb == 0)
            *(float4*)&z[((size_t)b * NPTS + row) * CDIM + cg * 16 + g * 4] = s;
    }
}

// ======================= K2b: z -> W,relu,BN,pool -> out ================================
__global__ __launch_bounds__(256) void k2b_gemm(const float* __restrict__ z,
                                                const float* __restrict__ W,
                                                const float* __restrict__ bias,
                                                const float* __restrict__ gamma,
                                                const float* __restrict__ rvar,
                                                float* __restrict__ out) {
    __shared__ __align__(16) float s_zz[128 * 64];   // 32 KB staged z tile
    __shared__ float s_red[2][256];
    const int b = blockIdx.x >> 3, nq = blockIdx.x & 7;
    const int t = threadIdx.x;
    const float* zb = z + ((size_t)b * NPTS + nq * 128) * CDIM;
#pragma unroll
    for (int qq = 0; qq < 8; qq++) {                 // coalesced float4 staging
        int e = qq * 256 + t;
        *(float4*)&s_zz[e * 4] = *(const float4*)&zb[e * 4];
    }
    __syncthreads();
    const int o2 = t & 63, h = t >> 6;               // o in {o2, o2+64}; 4 row-groups
    float4 w0[16], w1[16];
#pragma unroll
    for (int c4 = 0; c4 < 16; c4++) {
        w0[c4] = *(const float4*)&W[(size_t)o2 * CDIM + c4 * 4];
        w1[c4] = *(const float4*)&W[(size_t)(o2 + 64) * CDIM + c4 * 4];
    }
    const float b0 = bias[o2], b1 = bias[o2 + 64];
    float r0 = 0.f, r1 = 0.f;
    for (int r = 0; r < 32; r++) {
        const float* zr = &s_zz[(h * 32 + r) * 64];  // wave-uniform -> LDS broadcast
        float a0 = 0.f, a1 = 0.f;
#pragma unroll
        for (int c4 = 0; c4 < 16; c4++) {
            float4 zv = *(const float4*)&zr[c4 * 4];
            a0 += w0[c4].x * zv.x + w0[c4].y * zv.y + w0[c4].z * zv.z + w0[c4].w * zv.w;
            a1 += w1[c4].x * zv.x + w1[c4].y * zv.y + w1[c4].z * zv.z + w1[c4].w * zv.w;
        }
        r0 += fmaxf(a0 * (1.f / KNN) + b0, 0.f);
        r1 += fmaxf(a1 * (1.f / KNN) + b1, 0.f);
    }
    s_red[0][t] = r0; s_red[1][t] = r1;
    __syncthreads();
    if (t < 128) {
        const int oo = t & 63, which = t >> 6;
        const int o = which * 64 + oo;
        float sum = s_red[which][oo] + s_red[which][64 + oo] +
                    s_red[which][128 + oo] + s_red[which][192 + oo];
        float scale = gamma[o] * rsqrtf(rvar[o] + BNEPS) * (1.f / NPTS);
        atomicAdd(&out[b * ODIM + o], sum * scale);
    }
}

// ======================= Fallback: round-1 fused kernel (no workspace) ==================
#define RTILE 8
#define APAD  1028
#define WPAD  132
#define POOLF (64 * WPAD)

__global__ __launch_bounds__(256) void gcn_main(
    const float* __restrict__ X, const float* __restrict__ W,
    const float* __restrict__ bias, const float* __restrict__ gamma,
    const float* __restrict__ rvar, float* __restrict__ out)
{
    __shared__ __align__(16) float s_pool[POOLF];
    __shared__ __align__(16) float s_fstage[4][APAD];
    __shared__ int   s_knn[RTILE][KNN];
    __shared__ float s_z[RTILE][CDIM];

    const int t = threadIdx.x;
    const int b = blockIdx.x >> 7;
    const int rtile = blockIdx.x & 127;
    const int r0 = rtile * RTILE;
    const float* Xb = X + (size_t)b * CDIM * NPTS;

    float acc[RTILE][4];
    float sqv[4];
#pragma unroll
    for (int r = 0; r < RTILE; r++)
#pragma unroll
        for (int u = 0; u < 4; u++) acc[r][u] = 0.f;
#pragma unroll
    for (int u = 0; u < 4; u++) sqv[u] = 0.f;

    for (int ch = 0; ch < 16; ch++) {
        const int c0 = ch * 4;
#pragma unroll
        for (int cc = 0; cc < 4; cc++) {
            float4 v = *(const float4*)(Xb + (size_t)(c0 + cc) * NPTS + 4 * t);
            *(float4*)&s_fstage[cc][4 * t] = v;
        }
        __syncthreads();
#pragma unroll
        for (int cc = 0; cc < 4; cc++) {
            float4 bv4 = *(const float4*)&s_fstage[cc][4 * t];
            float bv[4] = {bv4.x, bv4.y, bv4.z, bv4.w};
#pragma unroll
            for (int u = 0; u < 4; u++) sqv[u] += bv[u] * bv[u];
            const float* arow = Xb + (size_t)(c0 + cc) * NPTS + r0;
            float4 a0 = *(const float4*)(arow);
            float4 a1 = *(const float4*)(arow + 4);
            float av[8] = {a0.x, a0.y, a0.z, a0.w, a1.x, a1.y, a1.z, a1.w};
#pragma unroll
            for (int r = 0; r < RTILE; r++)
#pragma unroll
                for (int u = 0; u < 4; u++) acc[r][u] += av[r] * bv[u];
        }
        __syncthreads();
    }

    float* s_dist = s_pool;
#pragma unroll
    for (int r = 0; r < RTILE; r++) {
        const int rG = r0 + r;
        float d[4];
#pragma unroll
        for (int u = 0; u < 4; u++) {
            float dd = sqv[u] - 2.f * acc[r][u];
            d[u] = (4 * t + u == rG) ? __uint_as_float(0x7F800000u) : dd;
        }
        *(float4*)&s_dist[r * NPTS + 4 * t] = make_float4(d[0], d[1], d[2], d[3]);
    }
    __syncthreads();

    const int wave = t >> 6, lane = t & 63;
    const unsigned long long ltmask = (1ull << lane) - 1ull;
    for (int rr = 0; rr < 2; rr++) {
        const int row = wave * 2 + rr;
        unsigned key[16];
#pragma unroll
        for (int tt = 0; tt < 16; tt++) {
            unsigned u = __float_as_uint(s_dist[row * NPTS + tt * 64 + lane]);
            key[tt] = (u & 0x80000000u) ? ~u : (u | 0x80000000u);
        }
        unsigned lo = 0u, hi = 0xFFFFFFFFu;
        while (lo < hi) {
            unsigned mid = lo + ((hi - lo) >> 1);
            int cnt = 0;
#pragma unroll
            for (int tt = 0; tt < 16; tt++)
                cnt += __popcll(__ballot(key[tt] <= mid));
            if (cnt >= KNN) hi = mid; else lo = mid + 1;
        }
        const unsigned v49 = lo;
        int cntless = 0;
#pragma unroll
        for (int tt = 0; tt < 16; tt++)
            cntless += __popcll(__ballot(key[tt] < v49));
        const int need = KNN - cntless;
        int base = 0, eqtaken = 0;
#pragma unroll
        for (int tt = 0; tt < 16; tt++) {
            bool islt = key[tt] < v49;
            bool iseq = key[tt] == v49;
            unsigned long long meq = __ballot(iseq);
            int eqrank = eqtaken + __popcll(meq & ltmask);
            bool sel = islt || (iseq && (eqrank < need));
            unsigned long long msel = __ballot(sel);
            if (sel) {
                int pos = base + __popcll(msel & ltmask);
                s_knn[row][pos] = tt * 64 + lane;
            }
            base    += __popcll(msel);
            eqtaken += __popcll(meq);
        }
    }
    __syncthreads();

    float* astage = s_pool;
    float* s_redf = (float*)s_fstage;
    const int ar = t >> 5, acc8 = (t & 31) >> 2, ks = t & 3;
    for (int c0 = 0; c0 < CDIM; c0 += 8) {
#pragma unroll
        for (int qq = 0; qq < 8; qq++) {
            int if4 = qq * 256 + t;
            int cc = if4 >> 8, j4 = if4 & 255;
            float4 v = *(const float4*)(Xb + (size_t)(c0 + cc) * NPTS + 4 * j4);
            *(float4*)&astage[cc * APAD + 4 * j4] = v;
        }
        __syncthreads();
        float partial = 0.f;
        for (int k = ks; k < KNN; k += 4)
            partial += astage[acc8 * APAD + s_knn[ar][k]];
        s_redf[t] = partial;
        __syncthreads();
        if (t < 64) {
            int r = t >> 3, cc = t & 7;
            int bi = r * 32 + cc * 4;
            s_z[r][c0 + cc] = s_redf[bi] + s_redf[bi + 1] + s_redf[bi + 2] + s_redf[bi + 3];
        }
        __syncthreads();
    }

    float* wt = s_pool;
#pragma unroll 4
    for (int qq = 0; qq < 32; qq++) {
        int e = qq * 256 + t;
        int o = e >> 6, c = e & 63;
        wt[c * WPAD + o] = W[e];
    }
    __syncthreads();
    const int o = t & 127, rg = t >> 7;
    float facc[4] = {0.f, 0.f, 0.f, 0.f};
    for (int c = 0; c < CDIM; c += 4) {
        float w0 = wt[(c + 0) * WPAD + o], w1 = wt[(c + 1) * WPAD + o];
        float w2 = wt[(c + 2) * WPAD + o], w3 = wt[(c + 3) * WPAD + o];
#pragma unroll
        for (int qq = 0; qq < 4; qq++) {
            float4 zv = *(const float4*)&s_z[rg * 4 + qq][c];
            facc[qq] += w0 * zv.x + w1 * zv.y + w2 * zv.z + w3 * zv.w;
        }
    }
    const float bo = bias[o];
    float rsum = 0.f;
#pragma unroll
    for (int qq = 0; qq < 4; qq++) {
        float f = facc[qq] * (1.f / KNN) + bo;
        rsum += fmaxf(f, 0.f);
    }
    s_redf[t] = rsum;
    __syncthreads();
    if (t < 128) {
        float scale = gamma[t] * rsqrtf(rvar[t] + BNEPS) * (1.f / NPTS);
        atomicAdd(&out[b * ODIM + t], (s_redf[t] + s_redf[t + 128]) * scale);
    }
}

extern "C" void kernel_launch(void* const* d_in, const int* in_sizes, int n_in,
                              void* d_out, int out_size, void* d_ws, size_t ws_size,
                              hipStream_t stream) {
    const float* X     = (const float*)d_in[0];
    const float* W     = (const float*)d_in[1];
    const float* bias  = (const float*)d_in[2];
    const float* gamma = (const float*)d_in[3];
    const float* beta  = (const float*)d_in[4];
    const float* rmean = (const float*)d_in[5];
    const float* rvar  = (const float*)d_in[6];
    float* out = (float*)d_out;

    gcn_init<<<(BATCH * ODIM + 255) / 256, 256, 0, stream>>>(gamma, beta, rmean, rvar, out);
    if (ws_size >= WS_NEED) {
        uint8_t* ws = (uint8_t*)d_ws;
        uint32_t* XF  = (uint32_t*)(ws + O_XF);
        float*    sqw = (float*)(ws + O_SQ);
        int*      knn = (int*)(ws + O_KNN);
        float*    zw  = (float*)(ws + O_Z);
        k0_split<<<BATCH * 16, 256, 0, stream>>>(X, XF, sqw);
        k1_gram_select<<<BATCH * 64, 512, 0, stream>>>(XF, sqw, knn);
        k2a_aggregate<<<BATCH * 8, 256, 0, stream>>>(X, knn, zw);
        k2b_gemm<<<BATCH * 8, 256, 0, stream>>>(zw, W, bias, gamma, rvar, out);
    } else {
        gcn_main<<<BATCH * (NPTS / RTILE), 256, 0, stream>>>(X, W, bias, gamma, rvar, out);
    }
}

// Round 5
// 285.490 us; speedup vs baseline: 1.4907x; 1.4907x over previous
//
#include <hip/hip_runtime.h>
#include <stdint.h>

#define BATCH 64
#define CDIM  64
#define NPTS  1024
#define ODIM  128
#define KNN   49
#define KNNP  52      // padded knn row stride (16B-aligned: 52*4=208=16*13)
#define BNEPS 1e-5f

typedef __attribute__((ext_vector_type(8))) short bf16x8;   // 8 bf16 (4 VGPRs)
typedef __attribute__((ext_vector_type(4))) float f32x4;

// ---- workspace layout (bytes) ----
#define O_XF   0
#define SZ_XF  (BATCH*64*2*64*8*4)        // 16,777,216  bf16 hi/lo fragments
#define O_SQ   (O_XF + SZ_XF)
#define SZ_SQ  (BATCH*NPTS*4)             // 262,144    per-col squared norms
#define O_KNN  (O_SQ + SZ_SQ)
#define SZ_KNN (BATCH*NPTS*KNNP*4)        // 13,631,488 knn indices (padded)
#define O_Z    (O_KNN + SZ_KNN)
#define SZ_Z   (BATCH*NPTS*CDIM*4)        // 16,777,216 aggregated features
#define WS_NEED ((size_t)(O_Z + SZ_Z))    // 47,448,064

// out[b*O+o] = beta - gamma*mean*rsqrt(var+eps)   (BN constant of pooled mean)
__global__ void gcn_init(const float* __restrict__ gamma, const float* __restrict__ beta,
                         const float* __restrict__ rmean, const float* __restrict__ rvar,
                         float* __restrict__ out) {
    int i = blockIdx.x * 256 + threadIdx.x;
    if (i < BATCH * ODIM) {
        int o = i & (ODIM - 1);
        out[i] = beta[o] - gamma[o] * rmean[o] * rsqrtf(rvar[o] + BNEPS);
    }
}

// ======================= K0: bf16 hi/lo split + MFMA-fragment swizzle + sq ==============
__global__ __launch_bounds__(256) void k0_split(const float* __restrict__ X,
                                                uint32_t* __restrict__ XF,
                                                float* __restrict__ sq) {
    const int b    = blockIdx.x >> 4;
    const int t16  = (blockIdx.x & 15) * 4 + (threadIdx.x >> 6);
    const int lane = threadIdx.x & 63;
    const int n    = t16 * 16 + (lane & 15);
    const int cg   = lane >> 4;
    const float* Xb = X + (size_t)b * CDIM * NPTS;
    float s = 0.f;
    for (int ks = 0; ks < 2; ks++) {
        uint32_t hi[4], lo[4];
#pragma unroll
        for (int dj = 0; dj < 4; dj++) {
            uint32_t hw[2], lw[2];
#pragma unroll
            for (int e = 0; e < 2; e++) {
                int c = ks * 32 + cg * 8 + dj * 2 + e;
                float x = Xb[(size_t)c * NPTS + n];
                s += x * x;
                uint32_t u  = __float_as_uint(x);
                uint32_t hr = (u + 0x7FFFu + ((u >> 16) & 1u)) >> 16;   // RTNE bf16
                float    hf = __uint_as_float(hr << 16);
                uint32_t ul = __float_as_uint(x - hf);
                uint32_t lr = (ul + 0x7FFFu + ((ul >> 16) & 1u)) >> 16;
                hw[e] = hr; lw[e] = lr;
            }
            hi[dj] = hw[0] | (hw[1] << 16);
            lo[dj] = lw[0] | (lw[1] << 16);
        }
        size_t entry = ((size_t)(b * 64 + t16) * 2 + ks) * 64 + lane;
        uint32_t* p = XF + entry * 8;
        *(uint4*)p       = make_uint4(hi[0], hi[1], hi[2], hi[3]);
        *(uint4*)(p + 4) = make_uint4(lo[0], lo[1], lo[2], lo[3]);
    }
    s += __shfl_xor(s, 16, 64);
    s += __shfl_xor(s, 32, 64);
    if (lane < 16) sq[b * NPTS + n] = s;
}

// ======================= K1: MFMA Gram + 16-bit ballot-search 49-select -> knn ==========
// 512 threads (8 waves). Keys truncated to top-16 bits of the monotone map, packed
// 2 rows/uint (32 KB LDS). Select: interleaved 2-row binary search over the
// narrowed range [wave_min, max_of_lane_mins] -- ~6-9 iterations in 16-bit space.
__global__ __launch_bounds__(512, 6) void k1_gram_select(const uint32_t* __restrict__ XF,
                                                         const float* __restrict__ sq,
                                                         int* __restrict__ knn) {
    __shared__ uint32_t s_pk[8 * 1024];              // 32 KB packed keys
    const int b    = blockIdx.x >> 6;
    const int rt   = blockIdx.x & 63;                // 16-row tile
    const int wave = threadIdx.x >> 6, lane = threadIdx.x & 63;
    const int q = lane >> 4, l15 = lane & 15;

    // A fragments (rows rt*16..+15), shared by all waves
    bf16x8 ahi[2], alo[2];
#pragma unroll
    for (int ks = 0; ks < 2; ks++) {
        const uint32_t* p = XF + (((size_t)(b * 64 + rt) * 2 + ks) * 64 + lane) * 8;
        ahi[ks] = *(const bf16x8*)p;
        alo[ks] = *(const bf16x8*)(p + 4);
    }
    const float* sqb = sq + b * NPTS;

#pragma unroll
    for (int tt = 0; tt < 8; tt++) {                 // wave's 8 col-tiles
        const int t16 = wave * 8 + tt;
        f32x4 acc = {0.f, 0.f, 0.f, 0.f};
#pragma unroll
        for (int ks = 0; ks < 2; ks++) {
            const uint32_t* p = XF + (((size_t)(b * 64 + t16) * 2 + ks) * 64 + lane) * 8;
            bf16x8 bhi = *(const bf16x8*)p;
            bf16x8 blo = *(const bf16x8*)(p + 4);
            acc = __builtin_amdgcn_mfma_f32_16x16x32_bf16(ahi[ks], bhi, acc, 0, 0, 0);
            acc = __builtin_amdgcn_mfma_f32_16x16x32_bf16(alo[ks], bhi, acc, 0, 0, 0);
            acc = __builtin_amdgcn_mfma_f32_16x16x32_bf16(ahi[ks], blo, acc, 0, 0, 0);
        }
        const int col  = t16 * 16 + l15;
        const float sqv = sqb[col];
        uint32_t k16[4];
#pragma unroll
        for (int i = 0; i < 4; i++) {
            int row = q * 4 + i;                     // C layout: row=(lane>>4)*4+reg
            float d = sqv - 2.f * acc[i];            // sq_r dropped (row-monotone)
            if (col == rt * 16 + row) d = __uint_as_float(0x7F800000u);  // self
            uint32_t u = __float_as_uint(d);
            uint32_t key = ((int)u < 0) ? ~u : (u | 0x80000000u);
            k16[i] = key >> 16;                      // 16-bit monotone key
        }
        const int p0 = 2 * q, p1 = 2 * q + 1;        // row pairs (2-way wr conflict: free)
        s_pk[p0 * 1024 + (col ^ ((p0 & 3) << 3))] = k16[0] | (k16[1] << 16);
        s_pk[p1 * 1024 + (col ^ ((p1 & 3) << 3))] = k16[2] | (k16[3] << 16);
    }
    __syncthreads();

    // ---- load this wave's packed row-pair, unpack to 16-bit keys ----
    uint32_t k0r[16], k1r[16];
    {
        const int sw = (wave & 3) << 3;
#pragma unroll
        for (int tt = 0; tt < 16; tt++) {
            uint32_t pk = s_pk[wave * 1024 + ((tt * 64 + lane) ^ sw)];
            k0r[tt] = pk & 0xFFFFu;
            k1r[tt] = pk >> 16;
        }
    }

    // ---- narrowed bounds per row: lo = wave min, hi = max over lanes of lane-min ----
    uint32_t lo0, hi0, lo1, hi1;
    {
        uint32_t lm0 = k0r[0], lm1 = k1r[0];
#pragma unroll
        for (int tt = 1; tt < 16; tt++) {
            lm0 = k0r[tt] < lm0 ? k0r[tt] : lm0;
            lm1 = k1r[tt] < lm1 ? k1r[tt] : lm1;
        }
        uint32_t g0 = lm0, m0 = lm0, g1 = lm1, m1 = lm1;
#pragma unroll
        for (int off = 1; off < 64; off <<= 1) {
            uint32_t a0 = (uint32_t)__shfl_xor((int)g0, off, 64);
            uint32_t b0 = (uint32_t)__shfl_xor((int)m0, off, 64);
            uint32_t a1 = (uint32_t)__shfl_xor((int)g1, off, 64);
            uint32_t b1 = (uint32_t)__shfl_xor((int)m1, off, 64);
            g0 = a0 < g0 ? a0 : g0;  m0 = b0 > m0 ? b0 : m0;
            g1 = a1 < g1 ? a1 : g1;  m1 = b1 > m1 ? b1 : m1;
        }
        lo0 = g0; hi0 = m0;                          // cnt(<=m) >= 64 >= KNN
        lo1 = g1; hi1 = m1;
    }

    // ---- interleaved exact binary search (16-bit space, ~6-9 iters) ----
    for (int it = 0; it < 16; it++) {
        bool a0 = lo0 < hi0, a1 = lo1 < hi1;
        if (!a0 && !a1) break;
        uint32_t mid0 = (lo0 + hi0) >> 1;
        uint32_t mid1 = (lo1 + hi1) >> 1;
        int cnt0 = 0, cnt1 = 0;
#pragma unroll
        for (int tt = 0; tt < 16; tt++) {
            cnt0 += __popcll(__ballot(k0r[tt] <= mid0));
            cnt1 += __popcll(__ballot(k1r[tt] <= mid1));
        }
        if (a0) { if (cnt0 >= KNN) hi0 = mid0; else lo0 = mid0 + 1; }
        if (a1) { if (cnt1 >= KNN) hi1 = mid1; else lo1 = mid1 + 1; }
    }

    // ---- emit indices (ties broken by ascending index, matching lax.top_k) ----
    const unsigned long long ltmask = (1ull << lane) - 1ull;
#pragma unroll
    for (int r = 0; r < 2; r++) {
        const int row = wave * 2 + r;
        const uint32_t vstar = r ? lo1 : lo0;
        const uint32_t* k = r ? k1r : k0r;
        int cntless = 0;
#pragma unroll
        for (int tt = 0; tt < 16; tt++)
            cntless += __popcll(__ballot(k[tt] < vstar));
        const int need = KNN - cntless;
        int base = 0, eqtaken = 0;
        int* kout = knn + ((size_t)b * NPTS + rt * 16 + row) * KNNP;
#pragma unroll
        for (int tt = 0; tt < 16; tt++) {
            bool islt = k[tt] < vstar, iseq = k[tt] == vstar;
            unsigned long long meq = __ballot(iseq);
            int eqrank = eqtaken + __popcll(meq & ltmask);
            bool sel = islt || (iseq && eqrank < need);
            unsigned long long msel = __ballot(sel);
            if (sel) kout[base + __popcll(msel & ltmask)] = tt * 64 + lane;
            base    += __popcll(msel);
            eqtaken += __popcll(meq);
        }
    }
}

// ======================= K2a: neighbor aggregation -> z =================================
// lane = r2*16 + kb*4 + g : 4 rows per iteration, 2-step shuffle reduce over kb.
__global__ __launch_bounds__(256) void k2a_aggregate(const float* __restrict__ X,
                                                     const int* __restrict__ knn,
                                                     float* __restrict__ z) {
    __shared__ float XT[16 * 1024];                  // 64 KB, [n][16ch] quad-swizzled
    const int b = blockIdx.x >> 3, cg = (blockIdx.x >> 1) & 3, half = blockIdx.x & 1;
    const int t = threadIdx.x;
    const float* Xb = X + ((size_t)b * CDIM + cg * 16) * NPTS;
#pragma unroll
    for (int nn = 0; nn < 4; nn++) {                 // stage 16 ch x 1024 cols transposed
        int n = nn * 256 + t;
#pragma unroll
        for (int g = 0; g < 4; g++) {
            float4 v;
            v.x = Xb[(size_t)(4 * g + 0) * NPTS + n];
            v.y = Xb[(size_t)(4 * g + 1) * NPTS + n];
            v.z = Xb[(size_t)(4 * g + 2) * NPTS + n];
            v.w = Xb[(size_t)(4 * g + 3) * NPTS + n];
            int qp = g ^ ((n >> 1) & 3);             // full 32-bank spread for b128
            *(float4*)&XT[n * 16 + qp * 4] = v;
        }
    }
    __syncthreads();
    const int wave = t >> 6, lane = t & 63;
    const int r2 = lane >> 4, kb = (lane >> 2) & 3, g = lane & 3;
    for (int rr = 0; rr < 32; rr++) {                // 128 rows per wave, 4 at a time
        const int row = half * 512 + wave * 128 + rr * 4 + r2;
        const int* kr = knn + ((size_t)b * NPTS + row) * KNNP;
        float4 s = {0.f, 0.f, 0.f, 0.f};
#pragma unroll
        for (int cs = 0; cs < 3; cs++) {             // aligned dwordx4 knn loads
            int4 j4 = *(const int4*)&kr[(kb + 4 * cs) * 4];
            int js[4] = {j4.x, j4.y, j4.z, j4.w};
#pragma unroll
            for (int e = 0; e < 4; e++) {
                int j = js[e];
                float4 v = *(const float4*)&XT[j * 16 + ((g ^ ((j >> 1) & 3)) << 2)];
                s.x += v.x; s.y += v.y; s.z += v.z; s.w += v.w;
            }
        }
        if (kb == 0) {                               // tail k = 48
            int j = kr[48];
            float4 v = *(const float4*)&XT[j * 16 + ((g ^ ((j >> 1) & 3)) << 2)];
            s.x += v.x; s.y += v.y; s.z += v.z; s.w += v.w;
        }
#pragma unroll
        for (int off = 4; off <= 8; off <<= 1) {     // reduce over kb (bits [3:2])
            s.x += __shfl_xor(s.x, off, 64);
            s.y += __shfl_xor(s.y, off, 64);
            s.z += __shfl_xor(s.z, off, 64);
            s.w += __shfl_xor(s.w, off, 64);
        }
        if (kb == 0)
            *(float4*)&z[((size_t)b * NPTS + row) * CDIM + cg * 16 + g * 4] = s;
    }
}

// ======================= K2b: z -> W,relu,BN,pool -> out ================================
__global__ __launch_bounds__(256) void k2b_gemm(const float* __restrict__ z,
                                                const float* __restrict__ W,
                                                const float* __restrict__ bias,
                                                const float* __restrict__ gamma,
                                                const float* __restrict__ rvar,
                                                float* __restrict__ out) {
    __shared__ __align__(16) float s_zz[128 * 64];   // 32 KB staged z tile
    __shared__ float s_red[2][256];
    const int b = blockIdx.x >> 3, nq = blockIdx.x & 7;
    const int t = threadIdx.x;
    const float* zb = z + ((size_t)b * NPTS + nq * 128) * CDIM;
#pragma unroll
    for (int qq = 0; qq < 8; qq++) {                 // coalesced float4 staging
        int e = qq * 256 + t;
        *(float4*)&s_zz[e * 4] = *(const float4*)&zb[e * 4];
    }
    __syncthreads();
    const int o2 = t & 63, h = t >> 6;               // o in {o2, o2+64}; 4 row-groups
    float4 w0[16], w1[16];
#pragma unroll
    for (int c4 = 0; c4 < 16; c4++) {
        w0[c4] = *(const float4*)&W[(size_t)o2 * CDIM + c4 * 4];
        w1[c4] = *(const float4*)&W[(size_t)(o2 + 64) * CDIM + c4 * 4];
    }
    const float b0 = bias[o2], b1 = bias[o2 + 64];
    float r0 = 0.f, r1 = 0.f;
    for (int r = 0; r < 32; r++) {
        const float* zr = &s_zz[(h * 32 + r) * 64];  // wave-uniform -> LDS broadcast
        float a0 = 0.f, a1 = 0.f;
#pragma unroll
        for (int c4 = 0; c4 < 16; c4++) {
            float4 zv = *(const float4*)&zr[c4 * 4];
            a0 += w0[c4].x * zv.x + w0[c4].y * zv.y + w0[c4].z * zv.z + w0[c4].w * zv.w;
            a1 += w1[c4].x * zv.x + w1[c4].y * zv.y + w1[c4].z * zv.z + w1[c4].w * zv.w;
        }
        r0 += fmaxf(a0 * (1.f / KNN) + b0, 0.f);
        r1 += fmaxf(a1 * (1.f / KNN) + b1, 0.f);
    }
    s_red[0][t] = r0; s_red[1][t] = r1;
    __syncthreads();
    if (t < 128) {
        const int oo = t & 63, which = t >> 6;
        const int o = which * 64 + oo;
        float sum = s_red[which][oo] + s_red[which][64 + oo] +
                    s_red[which][128 + oo] + s_red[which][192 + oo];
        float scale = gamma[o] * rsqrtf(rvar[o] + BNEPS) * (1.f / NPTS);
        atomicAdd(&out[b * ODIM + o], sum * scale);
    }
}

// ======================= Fallback: round-1 fused kernel (no workspace) ==================
#define RTILE 8
#define APAD  1028
#define WPAD  132
#define POOLF (64 * WPAD)

__global__ __launch_bounds__(256) void gcn_main(
    const float* __restrict__ X, const float* __restrict__ W,
    const float* __restrict__ bias, const float* __restrict__ gamma,
    const float* __restrict__ rvar, float* __restrict__ out)
{
    __shared__ __align__(16) float s_pool[POOLF];
    __shared__ __align__(16) float s_fstage[4][APAD];
    __shared__ int   s_knn[RTILE][KNN];
    __shared__ float s_z[RTILE][CDIM];

    const int t = threadIdx.x;
    const int b = blockIdx.x >> 7;
    const int rtile = blockIdx.x & 127;
    const int r0 = rtile * RTILE;
    const float* Xb = X + (size_t)b * CDIM * NPTS;

    float acc[RTILE][4];
    float sqv[4];
#pragma unroll
    for (int r = 0; r < RTILE; r++)
#pragma unroll
        for (int u = 0; u < 4; u++) acc[r][u] = 0.f;
#pragma unroll
    for (int u = 0; u < 4; u++) sqv[u] = 0.f;

    for (int ch = 0; ch < 16; ch++) {
        const int c0 = ch * 4;
#pragma unroll
        for (int cc = 0; cc < 4; cc++) {
            float4 v = *(const float4*)(Xb + (size_t)(c0 + cc) * NPTS + 4 * t);
            *(float4*)&s_fstage[cc][4 * t] = v;
        }
        __syncthreads();
#pragma unroll
        for (int cc = 0; cc < 4; cc++) {
            float4 bv4 = *(const float4*)&s_fstage[cc][4 * t];
            float bv[4] = {bv4.x, bv4.y, bv4.z, bv4.w};
#pragma unroll
            for (int u = 0; u < 4; u++) sqv[u] += bv[u] * bv[u];
            const float* arow = Xb + (size_t)(c0 + cc) * NPTS + r0;
            float4 a0 = *(const float4*)(arow);
            float4 a1 = *(const float4*)(arow + 4);
            float av[8] = {a0.x, a0.y, a0.z, a0.w, a1.x, a1.y, a1.z, a1.w};
#pragma unroll
            for (int r = 0; r < RTILE; r++)
#pragma unroll
                for (int u = 0; u < 4; u++) acc[r][u] += av[r] * bv[u];
        }
        __syncthreads();
    }

    float* s_dist = s_pool;
#pragma unroll
    for (int r = 0; r < RTILE; r++) {
        const int rG = r0 + r;
        float d[4];
#pragma unroll
        for (int u = 0; u < 4; u++) {
            float dd = sqv[u] - 2.f * acc[r][u];
            d[u] = (4 * t + u == rG) ? __uint_as_float(0x7F800000u) : dd;
        }
        *(float4*)&s_dist[r * NPTS + 4 * t] = make_float4(d[0], d[1], d[2], d[3]);
    }
    __syncthreads();

    const int wave = t >> 6, lane = t & 63;
    const unsigned long long ltmask = (1ull << lane) - 1ull;
    for (int rr = 0; rr < 2; rr++) {
        const int row = wave * 2 + rr;
        unsigned key[16];
#pragma unroll
        for (int tt = 0; tt < 16; tt++) {
            unsigned u = __float_as_uint(s_dist[row * NPTS + tt * 64 + lane]);
            key[tt] = (u & 0x80000000u) ? ~u : (u | 0x80000000u);
        }
        unsigned lo = 0u, hi = 0xFFFFFFFFu;
        while (lo < hi) {
            unsigned mid = lo + ((hi - lo) >> 1);
            int cnt = 0;
#pragma unroll
            for (int tt = 0; tt < 16; tt++)
                cnt += __popcll(__ballot(key[tt] <= mid));
            if (cnt >= KNN) hi = mid; else lo = mid + 1;
        }
        const unsigned v49 = lo;
        int cntless = 0;
#pragma unroll
        for (int tt = 0; tt < 16; tt++)
            cntless += __popcll(__ballot(key[tt] < v49));
        const int need = KNN - cntless;
        int base = 0, eqtaken = 0;
#pragma unroll
        for (int tt = 0; tt < 16; tt++) {
            bool islt = key[tt] < v49;
            bool iseq = key[tt] == v49;
            unsigned long long meq = __ballot(iseq);
            int eqrank = eqtaken + __popcll(meq & ltmask);
            bool sel = islt || (iseq && (eqrank < need));
            unsigned long long msel = __ballot(sel);
            if (sel) {
                int pos = base + __popcll(msel & ltmask);
                s_knn[row][pos] = tt * 64 + lane;
            }
            base    += __popcll(msel);
            eqtaken += __popcll(meq);
        }
    }
    __syncthreads();

    float* astage = s_pool;
    float* s_redf = (float*)s_fstage;
    const int ar = t >> 5, acc8 = (t & 31) >> 2, ks = t & 3;
    for (int c0 = 0; c0 < CDIM; c0 += 8) {
#pragma unroll
        for (int qq = 0; qq < 8; qq++) {
            int if4 = qq * 256 + t;
            int cc = if4 >> 8, j4 = if4 & 255;
            float4 v = *(const float4*)(Xb + (size_t)(c0 + cc) * NPTS + 4 * j4);
            *(float4*)&astage[cc * APAD + 4 * j4] = v;
        }
        __syncthreads();
        float partial = 0.f;
        for (int k = ks; k < KNN; k += 4)
            partial += astage[acc8 * APAD + s_knn[ar][k]];
        s_redf[t] = partial;
        __syncthreads();
        if (t < 64) {
            int r = t >> 3, cc = t & 7;
            int bi = r * 32 + cc * 4;
            s_z[r][c0 + cc] = s_redf[bi] + s_redf[bi + 1] + s_redf[bi + 2] + s_redf[bi + 3];
        }
        __syncthreads();
    }

    float* wt = s_pool;
#pragma unroll 4
    for (int qq = 0; qq < 32; qq++) {
        int e = qq * 256 + t;
        int o = e >> 6, c = e & 63;
        wt[c * WPAD + o] = W[e];
    }
    __syncthreads();
    const int o = t & 127, rg = t >> 7;
    float facc[4] = {0.f, 0.f, 0.f, 0.f};
    for (int c = 0; c < CDIM; c += 4) {
        float w0 = wt[(c + 0) * WPAD + o], w1 = wt[(c + 1) * WPAD + o];
        float w2 = wt[(c + 2) * WPAD + o], w3 = wt[(c + 3) * WPAD + o];
#pragma unroll
        for (int qq = 0; qq < 4; qq++) {
            float4 zv = *(const float4*)&s_z[rg * 4 + qq][c];
            facc[qq] += w0 * zv.x + w1 * zv.y + w2 * zv.z + w3 * zv.w;
        }
    }
    const float bo = bias[o];
    float rsum = 0.f;
#pragma unroll
    for (int qq = 0; qq < 4; qq++) {
        float f = facc[qq] * (1.f / KNN) + bo;
        rsum += fmaxf(f, 0.f);
    }
    s_redf[t] = rsum;
    __syncthreads();
    if (t < 128) {
        float scale = gamma[t] * rsqrtf(rvar[t] + BNEPS) * (1.f / NPTS);
        atomicAdd(&out[b * ODIM + t], (s_redf[t] + s_redf[t + 128]) * scale);
    }
}

extern "C" void kernel_launch(void* const* d_in, const int* in_sizes, int n_in,
                              void* d_out, int out_size, void* d_ws, size_t ws_size,
                              hipStream_t stream) {
    const float* X     = (const float*)d_in[0];
    const float* W     = (const float*)d_in[1];
    const float* bias  = (const float*)d_in[2];
    const float* gamma = (const float*)d_in[3];
    const float* beta  = (const float*)d_in[4];
    const float* rmean = (const float*)d_in[5];
    const float* rvar  = (const float*)d_in[6];
    float* out = (float*)d_out;

    gcn_init<<<(BATCH * ODIM + 255) / 256, 256, 0, stream>>>(gamma, beta, rmean, rvar, out);
    if (ws_size >= WS_NEED) {
        uint8_t* ws = (uint8_t*)d_ws;
        uint32_t* XF  = (uint32_t*)(ws + O_XF);
        float*    sqw = (float*)(ws + O_SQ);
        int*      knn = (int*)(ws + O_KNN);
        float*    zw  = (float*)(ws + O_Z);
        k0_split<<<BATCH * 16, 256, 0, stream>>>(X, XF, sqw);
        k1_gram_select<<<BATCH * 64, 512, 0, stream>>>(XF, sqw, knn);
        k2a_aggregate<<<BATCH * 8, 256, 0, stream>>>(X, knn, zw);
        k2b_gemm<<<BATCH * 8, 256, 0, stream>>>(zw, W, bias, gamma, rvar, out);
    } else {
        gcn_main<<<BATCH * (NPTS / RTILE), 256, 0, stream>>>(X, W, bias, gamma, rvar, out);
    }
}